// Round 14
// baseline (211.661 us; speedup 1.0000x reference)
//
#include <hip/hip_runtime.h>
#include <math.h>

typedef unsigned short ushort_t;
typedef unsigned int uint_t;
typedef __attribute__((ext_vector_type(8))) short s8v;
typedef __attribute__((ext_vector_type(4))) float f4;

#define NPIX 65536
#define EPS_ 1e-5f

__device__ __forceinline__ float bf2f(ushort_t u){ return __uint_as_float(((uint_t)u)<<16); }
__device__ __forceinline__ ushort_t f2bf(float f){
  uint_t u = __float_as_uint(f);
  uint_t r = (u + 0x7fffu + ((u>>16)&1u)) >> 16;
  return (ushort_t)r;
}
__device__ __forceinline__ float bflo(uint_t p){ return __uint_as_float(p<<16); }
__device__ __forceinline__ float bfhi(uint_t p){ return __uint_as_float(p & 0xffff0000u); }
__device__ __forceinline__ uint_t packbf(float a, float b){ return (uint_t)f2bf(a) | ((uint_t)f2bf(b)<<16); }

__device__ __forceinline__ f4 MFMA(s8v a, s8v b, f4 c){
  return __builtin_amdgcn_mfma_f32_16x16x32_bf16(a, b, c, 0, 0, 0);
}

__device__ __forceinline__ float wave_sum(float v){
  #pragma unroll
  for(int m=32;m>=1;m>>=1) v += __shfl_xor(v, m, 64);
  return v;
}

// ---------------- K1: single-pass GN sums + col partials + row pools ----------------
__global__ __launch_bounds__(256) void k1_stats(const float* __restrict__ u,
    float* __restrict__ part, float* __restrict__ pc, float* __restrict__ poolx){
  int blk = blockIdx.x; int b = blk>>8; int c = (blk>>2)&63; int iq = blk&3;
  int t = threadIdx.x; int lane = t&63; int w = t>>6;
  const float* up = u + ((size_t)(b*64+c))*NPIX + iq*64*256;
  __shared__ float sCol[4][256];
  __shared__ float red[8];
  float4 cs4 = {0.f,0.f,0.f,0.f};
  float ss = 0.f;
  #pragma unroll 4
  for(int r16=0;r16<16;r16++){
    int r = w*16 + r16;
    float4 v = *(const float4*)(up + r*256 + lane*4);
    cs4.x+=v.x; cs4.y+=v.y; cs4.z+=v.z; cs4.w+=v.w;
    ss += v.x*v.x+v.y*v.y+v.z*v.z+v.w*v.w;
    float rs = wave_sum(v.x+v.y+v.z+v.w);
    if(lane==0) poolx[(b*256 + iq*64 + r)*64 + c] = rs*(1.f/256.f);
  }
  *(float4*)&sCol[w][lane*4] = cs4;
  float ssw = wave_sum(ss);
  if(lane==0) red[w] = ssw;
  __syncthreads();
  float colsum = sCol[0][t]+sCol[1][t]+sCol[2][t]+sCol[3][t];
  pc[((b*64+c)*4+iq)*256 + t] = colsum;
  float s1 = wave_sum(colsum);
  if(lane==0) red[4+w] = s1;
  __syncthreads();
  if(t==0){
    part[((b*64+c)*4+iq)*2]   = red[4]+red[5]+red[6]+red[7];
    part[((b*64+c)*4+iq)*2+1] = red[0]+red[1]+red[2]+red[3];
  }
}

// ---------------- K8a: GN finalize + fold GN into w_in_proj + w2 bf16 ----------------
__global__ __launch_bounds__(256) void k8a_fold(const float* __restrict__ part,
    const float* __restrict__ gnw, const float* __restrict__ gnb,
    const float* __restrict__ w_in_proj, const float* __restrict__ out_w2,
    float* __restrict__ gnmv, ushort_t* __restrict__ wpb,
    float* __restrict__ c0g, ushort_t* __restrict__ w2b){
  int b = blockIdx.x; int t = threadIdx.x;
  __shared__ float scs[64], shs[64], sMV[2];
  if(t<64){
    float S1=0.f, S2=0.f;
    #pragma unroll
    for(int q=0;q<4;q++){
      S1 += part[((b*64+t)*4+q)*2];
      S2 += part[((b*64+t)*4+q)*2+1];
    }
    S1 = wave_sum(S1); S2 = wave_sum(S2);
    if(t==0){
      const float inv = 1.f/4194304.f;
      float m = S1*inv; float v = S2*inv - m*m;
      float rs = rsqrtf(v + EPS_);
      gnmv[b*2] = m; gnmv[b*2+1] = rs;
      sMV[0] = m; sMV[1] = rs;
    }
  }
  __syncthreads();
  if(t<64){
    float sc = sMV[1]*gnw[t];
    scs[t] = sc; shs[t] = gnb[t] - sMV[0]*sc;
  }
  __syncthreads();
  int oc = t>>1, h = t&1;
  float c0 = 0.f;
  for(int k=0;k<32;k++){
    int ch = h*32 + k;
    float wv = w_in_proj[oc*64 + ch];
    wpb[((size_t)b*128 + oc)*64 + ch] = f2bf(wv*scs[ch]);
    c0 += wv*shs[ch];
  }
  c0 += __shfl_xor(c0, 1, 64);
  if(h==0) c0g[b*128 + oc] = c0;
  if(b==0){
    for(int e=t;e<4096;e+=256) w2b[e] = f2bf(out_w2[e]);
  }
}

// ---------------- K8b: fold InstanceNorm into out_w1 ----------------
__global__ void k8b_fold(const float* __restrict__ istat,
    const float* __restrict__ out_w1, ushort_t* __restrict__ W1b,
    float* __restrict__ bias1){
  int b = blockIdx.x; int t = threadIdx.x;
  __shared__ float ms[128], rss[128];
  ms[t] = istat[(b*128+t)*2];       rss[t] = istat[(b*128+t)*2+1];
  ms[64+t] = istat[(b*128+64+t)*2]; rss[64+t] = istat[(b*128+64+t)*2+1];
  __syncthreads();
  float bias = 0.f;
  for(int ch=0;ch<128;ch++){
    float wv = out_w1[t*128 + ch];
    float wr = wv*rss[ch];
    W1b[((size_t)b*64 + t)*128 + ch] = f2bf(wr);
    bias += wr*ms[ch];
  }
  bias1[b*64 + t] = bias;
}

// ---------------- K3: MFMA pooled-path MLP chain ----------------
__global__ __launch_bounds__(256) void k3_mfma(
    const float* __restrict__ poolx, const float* __restrict__ pc,
    const float* __restrict__ gnmv,
    const float* __restrict__ gnw, const float* __restrict__ gnb,
    const float* __restrict__ w_to_in,
    const float* __restrict__ xwin, const float* __restrict__ xlg, const float* __restrict__ xlb,
    const float* __restrict__ xw1, const float* __restrict__ xw2, const float* __restrict__ xb2,
    const float* __restrict__ ywin, const float* __restrict__ ylg, const float* __restrict__ ylb,
    const float* __restrict__ yw1, const float* __restrict__ yw2, const float* __restrict__ yb2,
    float* __restrict__ ux, float* __restrict__ uy){
  int blk = blockIdx.x;
  int side = blk>>3; int b = (blk>>1)&3; int mt = blk&1;
  int i0 = mt*128;
  const float* win = side ? ywin : xwin;
  const float* lnw = side ? ylg  : xlg;
  const float* lnb = side ? ylb  : xlb;
  const float* w1  = side ? yw1  : xw1;
  const float* w2  = side ? yw2  : xw2;
  const float* b2  = side ? yb2  : xb2;
  float* outp = side ? uy : ux;

  __shared__ __align__(16) ushort_t sA[128*136];
  __shared__ __align__(16) ushort_t sB[128*136];
  __shared__ __align__(16) ushort_t sW[128*136];
  __shared__ float sGw[64], sGb[64], sLg[64], sLb[64];
  float* sF = (float*)sA;

  int t = threadIdx.x; int lane = t&63; int w = t>>6; int lr = lane&15; int lgq = lane>>4;
  const f4 fz = {0.f,0.f,0.f,0.f};

  if(t<64){ sGw[t]=gnw[t]; sGb[t]=gnb[t]; sLg[t]=lnw[t]; sLb[t]=lnb[t]; }
  for(int e=t;e<2048;e+=256){
    int r = e>>5, c2 = e&31;
    *(uint_t*)&sW[r*136 + c2*2] = packbf(w_to_in[r*64 + c2*2], w_to_in[r*64 + c2*2 + 1]);
  }
  __syncthreads();
  {
    float mean = gnmv[b*2], rstd = gnmv[b*2+1];
    int chalf = t>>7, tok = t&127;
    if(side==0){
      const float* pb = poolx + ((size_t)(b*256 + i0 + tok))*64 + chalf*32;
      #pragma unroll 8
      for(int cc=0;cc<32;cc++){
        int c = chalf*32+cc;
        float pn = (pb[cc]-mean)*rstd*sGw[c] + sGb[c];
        sA[c*136 + tok] = f2bf(pn);
      }
    } else {
      #pragma unroll 4
      for(int cc=0;cc<32;cc++){
        int c = chalf*32+cc;
        const float* p = pc + ((size_t)(b*64+c)*4)*256 + (i0+tok);
        float pv = (p[0]+p[256]+p[512]+p[768])*(1.f/256.f);
        float pn = (pv-mean)*rstd*sGw[c] + sGb[c];
        sA[c*136 + tok] = f2bf(pn);
      }
    }
  }
  __syncthreads();
  {
    f4 acc[2][4];
    #pragma unroll
    for(int it=0;it<2;it++)
      #pragma unroll
      for(int nt=0;nt<4;nt++) acc[it][nt]=fz;
    #pragma unroll
    for(int kc=0;kc<2;kc++){
      s8v bf[4];
      #pragma unroll
      for(int nt=0;nt<4;nt++)
        bf[nt] = *(const s8v*)&sW[(nt*16+lr)*136 + kc*32 + lgq*8];
      #pragma unroll
      for(int it=0;it<2;it++){
        int tok = w*32 + it*16 + lr;
        s8v a;
        #pragma unroll
        for(int j=0;j<8;j++) a[j] = (short)sA[(kc*32+lgq*8+j)*136 + tok];
        #pragma unroll
        for(int nt=0;nt<4;nt++)
          acc[it][nt] = MFMA(a, bf[nt], acc[it][nt]);
      }
    }
    __syncthreads();
    #pragma unroll
    for(int it=0;it<2;it++)
      #pragma unroll
      for(int nt=0;nt<4;nt++){
        f4 v = acc[it][nt];
        uint2 pk; pk.x = packbf(v.x,v.y); pk.y = packbf(v.z,v.w);
        *(uint2*)&sB[(nt*16+lr)*136 + w*32 + it*16 + lgq*4] = pk;
      }
  }
  for(int e=t;e<2048;e+=256){
    int r = e>>5, c2 = e&31;
    *(uint_t*)&sW[r*136 + c2*2] = packbf(win[r*64 + c2*2], win[r*64 + c2*2 + 1]);
  }
  __syncthreads();
  {
    f4 acc[2][4];
    #pragma unroll
    for(int it=0;it<2;it++)
      #pragma unroll
      for(int nt=0;nt<4;nt++) acc[it][nt]=fz;
    #pragma unroll
    for(int kc=0;kc<2;kc++){
      s8v bf[4];
      #pragma unroll
      for(int nt=0;nt<4;nt++)
        bf[nt] = *(const s8v*)&sW[(nt*16+lr)*136 + kc*32 + lgq*8];
      #pragma unroll
      for(int it=0;it<2;it++){
        int tok = w*32 + it*16 + lr;
        s8v a;
        #pragma unroll
        for(int j=0;j<8;j++) a[j] = (short)sB[(kc*32+lgq*8+j)*136 + tok];
        #pragma unroll
        for(int nt=0;nt<4;nt++)
          acc[it][nt] = MFMA(bf[nt], a, acc[it][nt]);
      }
    }
    __syncthreads();
    #pragma unroll
    for(int it=0;it<2;it++)
      #pragma unroll
      for(int nt=0;nt<4;nt++)
        *(f4*)&sF[(size_t)(w*32+it*16+lr)*68 + nt*16 + lgq*4] = acc[it][nt];
  }
  __syncthreads();
  for(int e=t;e<4096;e+=256){
    int r = e>>5, c2 = e&31;
    *(uint_t*)&sW[r*136 + c2*2] = packbf(w1[r*64 + c2*2], w1[r*64 + c2*2 + 1]);
  }
  if(t<128){
    float s=0.f, ss=0.f;
    #pragma unroll 8
    for(int o=0;o<64;o++){ float v = sF[(size_t)t*68 + o]; s+=v; ss+=v*v; }
    float m2 = s*(1.f/64.f);
    float var = ss*(1.f/64.f) - m2*m2;
    float rs2 = rsqrtf(var + EPS_);
    #pragma unroll 8
    for(int o=0;o<64;o++){
      float lnv = (sF[(size_t)t*68 + o]-m2)*rs2*sLg[o] + sLb[o];
      sB[o*136 + t] = f2bf(lnv);
    }
  }
  __syncthreads();
  {
    f4 acc[2][8];
    #pragma unroll
    for(int it=0;it<2;it++)
      #pragma unroll
      for(int nt=0;nt<8;nt++) acc[it][nt]=fz;
    #pragma unroll
    for(int kc=0;kc<2;kc++){
      s8v bf[8];
      #pragma unroll
      for(int nt=0;nt<8;nt++)
        bf[nt] = *(const s8v*)&sW[(nt*16+lr)*136 + kc*32 + lgq*8];
      #pragma unroll
      for(int it=0;it<2;it++){
        int tok = w*32 + it*16 + lr;
        s8v a;
        #pragma unroll
        for(int j=0;j<8;j++) a[j] = (short)sB[(kc*32+lgq*8+j)*136 + tok];
        #pragma unroll
        for(int nt=0;nt<8;nt++)
          acc[it][nt] = MFMA(a, bf[nt], acc[it][nt]);
      }
    }
    __syncthreads();
    #pragma unroll
    for(int it=0;it<2;it++)
      #pragma unroll
      for(int nt=0;nt<8;nt++){
        f4 v = acc[it][nt];
        #pragma unroll
        for(int r=0;r<4;r++){
          float x = v[r];
          v[r] = 0.5f*x*(1.f + erff(x*0.70710678118654752f));
        }
        uint2 pk; pk.x = packbf(v[0],v[1]); pk.y = packbf(v[2],v[3]);
        *(uint2*)&sA[(nt*16+lr)*136 + w*32 + it*16 + lgq*4] = pk;
      }
  }
  __syncthreads();
  for(int e=t;e<8192;e+=256){
    int r = e>>6, c2 = e&63;
    *(uint_t*)&sW[r*136 + c2*2] = packbf(w2[r*128 + c2*2], w2[r*128 + c2*2 + 1]);
  }
  __syncthreads();
  {
    f4 acc[2][8];
    #pragma unroll
    for(int nt=0;nt<8;nt++){
      f4 bb = *(const f4*)&b2[nt*16 + lgq*4];
      acc[0][nt] = bb; acc[1][nt] = bb;
    }
    #pragma unroll
    for(int kc=0;kc<4;kc++){
      s8v bf[8];
      #pragma unroll
      for(int nt=0;nt<8;nt++)
        bf[nt] = *(const s8v*)&sW[(nt*16+lr)*136 + kc*32 + lgq*8];
      #pragma unroll
      for(int it=0;it<2;it++){
        int tok = w*32 + it*16 + lr;
        s8v a;
        #pragma unroll
        for(int j=0;j<8;j++) a[j] = (short)sA[(kc*32+lgq*8+j)*136 + tok];
        #pragma unroll
        for(int nt=0;nt<8;nt++)
          acc[it][nt] = MFMA(bf[nt], a, acc[it][nt]);
      }
    }
    #pragma unroll
    for(int it=0;it<2;it++){
      int tok = w*32 + it*16 + lr;
      #pragma unroll
      for(int nt=0;nt<8;nt++)
        *(f4*)&outp[((size_t)(b*256 + i0 + tok))*128 + nt*16 + lgq*4] = acc[it][nt];
    }
  }
}

// ---------------- K4: MFMA qk GEMM + fused RoPE ----------------
__global__ __launch_bounds__(256) void k4_gemm(
    const float* __restrict__ ux, const float* __restrict__ uy,
    const float* __restrict__ wqkx, const float* __restrict__ wqky,
    ushort_t* __restrict__ qxb, ushort_t* __restrict__ kxTb,
    ushort_t* __restrict__ qyb, ushort_t* __restrict__ kyTb){
  int blk = blockIdx.x;
  int nt = blk&3; int mt = (blk>>2)&1; int b = (blk>>3)&3; int side = blk>>5;
  const float* x  = (side? uy:ux) + (size_t)(b*256 + mt*128)*128;
  const float* wq = (side? wqky:wqkx) + (size_t)nt*128*128;
  ushort_t* qb  = side? qyb : qxb;
  ushort_t* kTb = side? kyTb : kxTb;

  __shared__ __align__(16) ushort_t sA[128*136];
  __shared__ __align__(16) ushort_t sB[128*136];

  int t = threadIdx.x; int lane = t&63; int w = t>>6; int lr = lane&15; int lg = lane>>4;
  for(int e=t;e<4096;e+=256){
    int row = e>>5, c4 = (e&31)*4;
    float4 v = *(const float4*)(x + row*128 + c4);
    uint2 pk; pk.x = packbf(v.x,v.y); pk.y = packbf(v.z,v.w);
    *(uint2*)&sA[row*136 + c4] = pk;
    float4 wv = *(const float4*)(wq + row*128 + c4);
    uint2 wk; wk.x = packbf(wv.x,wv.y); wk.y = packbf(wv.z,wv.w);
    *(uint2*)&sB[row*136 + c4] = wk;
  }
  __syncthreads();
  const f4 fz = {0.f,0.f,0.f,0.f};
  f4 acc[2][8];
  #pragma unroll
  for(int it=0;it<2;it++)
    #pragma unroll
    for(int n2=0;n2<8;n2++) acc[it][n2]=fz;
  #pragma unroll
  for(int kc=0;kc<4;kc++){
    s8v bf[8];
    #pragma unroll
    for(int n2=0;n2<8;n2++)
      bf[n2] = *(const s8v*)&sB[(n2*16+lr)*136 + kc*32 + lg*8];
    #pragma unroll
    for(int it=0;it<2;it++){
      s8v a = *(const s8v*)&sA[(w*32+it*16+lr)*136 + kc*32 + lg*8];
      #pragma unroll
      for(int n2=0;n2<8;n2++)
        acc[it][n2] = MFMA(a, bf[n2], acc[it][n2]);
    }
  }
  if(nt < 2){
    #pragma unroll
    for(int it=0;it<2;it++){
      #pragma unroll
      for(int n2=0;n2<8;n2++){
        int o = nt*128 + n2*16 + lr;
        int h = o>>6, dd = o&63, t32 = dd&31;
        float invf = expf(-(float)t32*(9.210340371976184f/32.f));
        size_t base = (size_t)(b*4+h)*16384;
        #pragma unroll
        for(int r=0;r<4;r++){
          int i = mt*128 + w*32 + it*16 + lg*4 + r;
          float f = (64.f/255.f)*(float)i*invf;
          float sn, cs; __sincosf(f, &sn, &cs);
          float pair = acc[it][n2^2][r];
          float rot = ((n2&2)==0)? -pair : pair;
          float v = acc[it][n2][r]*cs + rot*sn;
          qb[base + (size_t)i*64 + dd] = f2bf(v);
        }
      }
    }
  } else {
    __syncthreads();
    #pragma unroll
    for(int it=0;it<2;it++){
      #pragma unroll
      for(int n2=0;n2<8;n2++){
        int ol = n2*16 + lr;
        int o = nt*128 + ol;
        int t32 = o&31;
        float invf = expf(-(float)t32*(9.210340371976184f/32.f));
        #pragma unroll
        for(int r=0;r<4;r++){
          int il = w*32 + it*16 + lg*4 + r;
          int i = mt*128 + il;
          float f = (64.f/255.f)*(float)i*invf;
          float sn, cs; __sincosf(f, &sn, &cs);
          float pair = acc[it][n2^2][r];
          float rot = ((n2&2)==0)? -pair : pair;
          float v = acc[it][n2][r]*cs + rot*sn;
          sA[ol*136 + il] = f2bf(v);
        }
      }
    }
    __syncthreads();
    {
      int row = t>>1, half = t&1;
      int h = (nt-2)*2 + (row>>6), dd = row&63;
      ushort_t* dst = kTb + (size_t)(b*4+h)*16384 + (size_t)dd*256 + mt*128 + half*64;
      const ushort_t* src = &sA[row*136 + half*64];
      #pragma unroll
      for(int j=0;j<8;j++)
        *(uint4*)(dst + j*8) = *(const uint4*)(src + j*8);
    }
  }
}

// ---------------- K5s: row sums of KxT/KyT (rank-1 c0 term) ----------------
__global__ __launch_bounds__(256) void k5s_sums(const ushort_t* __restrict__ kxTb,
    const ushort_t* __restrict__ kyTb, float* __restrict__ ksum){
  int bh = blockIdx.x; int t = threadIdx.x;
  int row = t>>2, g = t&3;
  const ushort_t* kx = kxTb + (size_t)bh*16384 + row*256 + g*64;
  float s = 0.f;
  #pragma unroll
  for(int j=0;j<8;j++){
    uint4 v = *(const uint4*)(kx + j*8);
    s += bflo(v.x)+bfhi(v.x)+bflo(v.y)+bfhi(v.y)+bflo(v.z)+bfhi(v.z)+bflo(v.w)+bfhi(v.w);
  }
  s += __shfl_xor(s,1,64); s += __shfl_xor(s,2,64);
  if(g==0) ksum[bh*128 + row] = s;
  const ushort_t* ky = kyTb + (size_t)bh*16384 + row*256 + g*64;
  float s2 = 0.f;
  #pragma unroll
  for(int j=0;j<8;j++){
    uint4 v = *(const uint4*)(ky + j*8);
    s2 += bflo(v.x)+bfhi(v.x)+bflo(v.y)+bfhi(v.y)+bflo(v.z)+bfhi(v.z)+bflo(v.w)+bfhi(v.w);
  }
  s2 += __shfl_xor(s2,1,64); s2 += __shfl_xor(s2,2,64);
  if(g==0) ksum[bh*128 + 64 + row] = s2;
}

// ---------------- K7a: per-input-channel cores Chat[b][ch][h] = KxT * u_ch * Ky ----------------
__global__ __launch_bounds__(512) void k7a_core(
    const float* __restrict__ u,
    const ushort_t* __restrict__ kxTb, const ushort_t* __restrict__ kyTb,
    ushort_t* __restrict__ Cb){
  int blk = blockIdx.x; int b = blk>>6;
  const float* up = u + (size_t)blk*NPIX;
  __shared__ __align__(16) ushort_t su[2][64*264];
  __shared__ __align__(16) ushort_t sT1[4][64*68];
  int t = threadIdx.x; int w = t>>6; int lane = t&63; int lr = lane&15; int lg = lane>>4;
  int h = w>>1, sub = w&1;
  const ushort_t* KyT = kyTb + (size_t)(b*4+h)*16384;
  const ushort_t* KxT = kxTb + (size_t)(b*4+h)*16384;
  const f4 fz = {0.f,0.f,0.f,0.f};
  f4 cacc[2][4];
  #pragma unroll
  for(int it=0;it<2;it++)
    #pragma unroll
    for(int et=0;et<4;et++) cacc[it][et]=fz;

  auto stageld = [&](int jc, int buf){
    #pragma unroll
    for(int k=0;k<8;k++){
      int flat = k*512 + t;
      int row = flat>>6, col4 = flat&63;
      float4 v = *(const float4*)(up + (size_t)(jc*64+row)*256 + col4*4);
      uint2 pk; pk.x = packbf(v.x,v.y); pk.y = packbf(v.z,v.w);
      *(uint2*)&su[buf][row*264 + col4*4] = pk;
    }
  };
  stageld(0, 0);
  __syncthreads();
  for(int jc=0;jc<4;jc++){
    int cur = jc&1;
    f4 acc[2][4];
    #pragma unroll
    for(int jt=0;jt<2;jt++)
      #pragma unroll
      for(int et=0;et<4;et++) acc[jt][et]=fz;
    #pragma unroll
    for(int km=0;km<8;km++){
      s8v a0 = *(const s8v*)&su[cur][(sub*32+lr)*264 + km*32 + lg*8];
      s8v a1 = *(const s8v*)&su[cur][(sub*32+16+lr)*264 + km*32 + lg*8];
      #pragma unroll
      for(int et=0;et<4;et++){
        s8v bv = *(const s8v*)(KyT + (et*16+lr)*256 + km*32 + lg*8);
        acc[0][et] = MFMA(a0,bv,acc[0][et]);
        acc[1][et] = MFMA(a1,bv,acc[1][et]);
      }
    }
    #pragma unroll
    for(int jt=0;jt<2;jt++)
      #pragma unroll
      for(int et=0;et<4;et++){
        f4 v = acc[jt][et];
        uint2 pk; pk.x=packbf(v.x,v.y); pk.y=packbf(v.z,v.w);
        *(uint2*)&sT1[h][(et*16+lr)*68 + sub*32 + jt*16 + lg*4] = pk;
      }
    __syncthreads();
    if(jc<3) stageld(jc+1, cur^1);
    #pragma unroll
    for(int kj=0;kj<2;kj++){
      s8v a0 = *(const s8v*)(KxT + (size_t)(sub*32+lr)*256 + jc*64 + kj*32 + lg*8);
      s8v a1 = *(const s8v*)(KxT + (size_t)(sub*32+16+lr)*256 + jc*64 + kj*32 + lg*8);
      #pragma unroll
      for(int et=0;et<4;et++){
        s8v bv = *(const s8v*)&sT1[h][(et*16+lr)*68 + kj*32 + lg*8];
        cacc[0][et] = MFMA(a0,bv,cacc[0][et]);
        cacc[1][et] = MFMA(a1,bv,cacc[1][et]);
      }
    }
    __syncthreads();
  }
  ushort_t* cbase = Cb + ((size_t)blk*4 + h)*4096;
  #pragma unroll
  for(int it=0;it<2;it++)
    #pragma unroll
    for(int et=0;et<4;et++){
      f4 v = cacc[it][et];
      uint2 pk; pk.x=packbf(v.x,v.y); pk.y=packbf(v.z,v.w);
      *(uint2*)&cbase[(et*16+lr)*64 + sub*32 + it*16 + lg*4] = pk;
    }
}

// ---------------- K7m: mix cores across input channels (+rank-1 c0 term) ----------------
__global__ __launch_bounds__(256) void k7m_mix(
    const ushort_t* __restrict__ Cb, const ushort_t* __restrict__ wpb,
    const float* __restrict__ c0g, const float* __restrict__ ksum,
    ushort_t* __restrict__ cT){
  int blk = blockIdx.x; int bh = blk>>4; int et = blk&15;
  int b = bh>>2, h = bh&3;
  __shared__ __align__(16) ushort_t sC[64*264];
  __shared__ float sWf[32*64];
  __shared__ float sKx[64], sKy4[4];
  int t = threadIdx.x;
  #pragma unroll
  for(int k=0;k<8;k++){
    int flat = k*256 + t;
    int ic = flat>>5, q = flat&31;
    uint4 v = *(const uint4*)(Cb + ((size_t)(b*64+ic)*4 + h)*4096 + et*256 + q*8);
    *(uint4*)&sC[ic*264 + q*8] = v;
  }
  for(int e=t;e<2048;e+=256){
    int ch = e>>6, ic = e&63;
    sWf[e] = bf2f(wpb[((size_t)b*128 + h*32 + ch)*64 + ic]);
  }
  if(t<64) sKx[t] = ksum[bh*128 + t];
  if(t<4)  sKy4[t] = ksum[bh*128 + 64 + et*4 + t];
  __syncthreads();
  int chg = t>>5, edq = t&31, ed0 = edq*8;
  float c0v[4];
  #pragma unroll
  for(int cc=0;cc<4;cc++) c0v[cc] = c0g[b*128 + h*32 + chg*4 + cc];
  float acc[4][8];
  #pragma unroll
  for(int j=0;j<8;j++){
    int ed = ed0 + j;
    float r1 = sKy4[ed>>6]*sKx[ed&63];
    #pragma unroll
    for(int cc=0;cc<4;cc++) acc[cc][j] = c0v[cc]*r1;
  }
  for(int ic=0;ic<64;ic++){
    uint4 cv = *(const uint4*)&sC[ic*264 + ed0];
    float x[8];
    x[0]=bflo(cv.x); x[1]=bfhi(cv.x); x[2]=bflo(cv.y); x[3]=bfhi(cv.y);
    x[4]=bflo(cv.z); x[5]=bfhi(cv.z); x[6]=bflo(cv.w); x[7]=bfhi(cv.w);
    #pragma unroll
    for(int cc=0;cc<4;cc++){
      float wv = sWf[(chg*4+cc)*64 + ic];
      #pragma unroll
      for(int j=0;j<8;j++) acc[cc][j] += wv*x[j];
    }
  }
  #pragma unroll
  for(int cc=0;cc<4;cc++){
    uint2 p0, p1;
    p0.x = packbf(acc[cc][0],acc[cc][1]); p0.y = packbf(acc[cc][2],acc[cc][3]);
    p1.x = packbf(acc[cc][4],acc[cc][5]); p1.y = packbf(acc[cc][6],acc[cc][7]);
    ushort_t* dst = cT + ((size_t)bh*32 + chg*4+cc)*4096 + et*256 + ed0;
    *(uint2*)(dst) = p0;
    *(uint2*)(dst+4) = p1;
  }
}

// ---------------- K7b: expand out_c = Qx core_c Qy^T + stats ----------------
__global__ __launch_bounds__(256) void k7b_heavy(
    const ushort_t* __restrict__ cT,
    const ushort_t* __restrict__ qxb, const ushort_t* __restrict__ qyb,
    ushort_t* __restrict__ up2, float* __restrict__ istat){
  int blk = blockIdx.x;
  int c = blk & 31; int h = (blk>>5)&3; int b = blk>>7;
  int bh = b*4 + h; int ch = h*32 + c;
  const ushort_t* Qx  = qxb + (size_t)bh*16384;
  const ushort_t* Qy  = qyb + (size_t)bh*16384;
  const ushort_t* cTc = cT + (size_t)(bh*32 + c)*4096;
  ushort_t* out_c = up2 + (size_t)(b*128 + ch)*NPIX;

  __shared__ __align__(16) ushort_t sP[256*72];
  __shared__ float sRed[8];

  int t = threadIdx.x; int w = t>>6; int lane = t&63; int lr = lane&15; int lg = lane>>4;
  const f4 fz = {0.f,0.f,0.f,0.f};
  {
    s8v aF[4][2];
    #pragma unroll
    for(int me=0;me<4;me++)
      #pragma unroll
      for(int kd=0;kd<2;kd++)
        aF[me][kd] = *(const s8v*)(cTc + (me*16+lr)*64 + kd*32 + lg*8);
    #pragma unroll
    for(int it=0;it<4;it++){
      s8v b0 = *(const s8v*)(Qx + (w*64+it*16+lr)*64 + lg*8);
      s8v b1 = *(const s8v*)(Qx + (w*64+it*16+lr)*64 + 32 + lg*8);
      #pragma unroll
      for(int me=0;me<4;me++){
        f4 pv = MFMA(aF[me][0], b0, fz);
        pv = MFMA(aF[me][1], b1, pv);
        uint2 pk; pk.x=packbf(pv.x,pv.y); pk.y=packbf(pv.z,pv.w);
        *(uint2*)&sP[(w*64+it*16+lr)*72 + me*16 + lg*4] = pk;
      }
    }
  }
  __syncthreads();
  float lsum=0.f, lssq=0.f;
  {
    s8v aP[4][2];
    #pragma unroll
    for(int it=0;it<4;it++)
      #pragma unroll
      for(int ke=0;ke<2;ke++)
        aP[it][ke] = *(const s8v*)&sP[(w*64+it*16+lr)*72 + ke*32 + lg*8];
    for(int lt=0;lt<4;lt++){
      s8v bq[4][2];
      #pragma unroll
      for(int nt=0;nt<4;nt++)
        #pragma unroll
        for(int ke=0;ke<2;ke++)
          bq[nt][ke] = *(const s8v*)(Qy + (lt*64+nt*16+lr)*64 + ke*32 + lg*8);
      #pragma unroll
      for(int it=0;it<4;it++){
        #pragma unroll
        for(int nt=0;nt<4;nt++){
          f4 o = MFMA(bq[nt][0], aP[it][0], fz);
          o = MFMA(bq[nt][1], aP[it][1], o);
          lsum += o[0]+o[1]+o[2]+o[3];
          lssq += o[0]*o[0]+o[1]*o[1]+o[2]*o[2]+o[3]*o[3];
          uint2 pk; pk.x = packbf(o[0],o[1]); pk.y = packbf(o[2],o[3]);
          *(uint2*)(out_c + (size_t)(w*64 + it*16 + lr)*256 + lt*64 + nt*16 + lg*4) = pk;
        }
      }
    }
  }
  float a1 = wave_sum(lsum), a2 = wave_sum(lssq);
  if(lane==0){ sRed[w]=a1; sRed[4+w]=a2; }
  __syncthreads();
  if(t==0){
    float S = sRed[0]+sRed[1]+sRed[2]+sRed[3];
    float SS = sRed[4]+sRed[5]+sRed[6]+sRed[7];
    float m = S*(1.f/65536.f);
    float var = SS*(1.f/65536.f) - m*m;
    istat[(b*128+ch)*2] = m;
    istat[(b*128+ch)*2+1] = rsqrtf(var + EPS_);
  }
}

// ---------------- KF: MFMA InstanceNorm(folded)+conv1-GELU-conv2+residual ----------------
// 256-px tiles (grid 1024), pitch 268, LDS 68.6 KB -> 2 blocks/CU
__global__ __launch_bounds__(256) void kf_out(
    const ushort_t* __restrict__ up2, const ushort_t* __restrict__ W1b,
    const float* __restrict__ bias1, const ushort_t* __restrict__ w2b,
    const float* __restrict__ u, float* __restrict__ out){
  int blk = blockIdx.x;
  int b = blk>>8; int pix0 = (blk&255)<<8;
  __shared__ __align__(16) unsigned char smraw[128*268*2];
  ushort_t* sX = (ushort_t*)smraw;   // [128ch][268]
  ushort_t* sG = (ushort_t*)smraw;   // [64hid][268]
  float* sO = (float*)smraw;         // [64oc][268] f32 (same 68608 B)
  int t = threadIdx.x; int lane = t&63; int w = t>>6; int lr = lane&15; int lg = lane>>4;
  // stage up2 tile [128ch][256px]
  {
    int ch = t>>4; int px = (t&15)*16;
    #pragma unroll
    for(int it=0; it<8; it++){
      int c = it*16 + ch;
      const ushort_t* src = up2 + ((size_t)(b*128+c))*NPIX + pix0 + px;
      uint4 v0 = *(const uint4*)(src);
      uint4 v1 = *(const uint4*)(src + 8);
      uint2 a0; a0.x=v0.x; a0.y=v0.y;
      uint2 a1; a1.x=v0.z; a1.y=v0.w;
      uint2 a2; a2.x=v1.x; a2.y=v1.y;
      uint2 a3; a3.x=v1.z; a3.y=v1.w;
      *(uint2*)&sX[c*268 + px]      = a0;
      *(uint2*)&sX[c*268 + px + 4]  = a1;
      *(uint2*)&sX[c*268 + px + 8]  = a2;
      *(uint2*)&sX[c*268 + px + 12] = a3;
    }
  }
  __syncthreads();
  // GEMM1: D1[256px][64hid], K=128ch; wave w owns px [w*64,+64)
  const ushort_t* w1p = W1b + (size_t)b*64*128;
  f4 g[4][4];
  #pragma unroll
  for(int it=0;it<4;it++)
    #pragma unroll
    for(int nt=0;nt<4;nt++){
      float bv = -bias1[b*64 + nt*16 + lr];
      f4 ci = {bv,bv,bv,bv};
      g[it][nt] = ci;
    }
  #pragma unroll
  for(int kc=0;kc<4;kc++){
    s8v bf[4];
    #pragma unroll
    for(int nt=0;nt<4;nt++)
      bf[nt] = *(const s8v*)(w1p + (nt*16+lr)*128 + kc*32 + lg*8);
    #pragma unroll
    for(int it=0;it<4;it++){
      int pix = w*64 + it*16 + lr;
      s8v a;
      #pragma unroll
      for(int j=0;j<8;j++) a[j] = (short)sX[(kc*32+lg*8+j)*268 + pix];
      #pragma unroll
      for(int nt=0;nt<4;nt++)
        g[it][nt] = MFMA(a, bf[nt], g[it][nt]);
    }
  }
  // GELU (erf)
  #pragma unroll
  for(int it=0;it<4;it++)
    #pragma unroll
    for(int nt=0;nt<4;nt++){
      f4 v = g[it][nt];
      #pragma unroll
      for(int r=0;r<4;r++){
        float x = v[r];
        v[r] = 0.5f*x*(1.f + erff(x*0.70710678118654752f));
      }
      g[it][nt] = v;
    }
  __syncthreads();   // all sX reads done
  // write sG[64hid][268]
  #pragma unroll
  for(int it=0;it<4;it++)
    #pragma unroll
    for(int nt=0;nt<4;nt++){
      f4 v = g[it][nt];
      uint2 pk; pk.x = packbf(v.x,v.y); pk.y = packbf(v.z,v.w);
      *(uint2*)&sG[(nt*16+lr)*268 + w*64 + it*16 + lg*4] = pk;
    }
  __syncthreads();
  // GEMM2: D2[256px][64oc], K=64hid
  f4 o2[4][4];
  const f4 fz = {0.f,0.f,0.f,0.f};
  #pragma unroll
  for(int it=0;it<4;it++)
    #pragma unroll
    for(int nt=0;nt<4;nt++) o2[it][nt]=fz;
  #pragma unroll
  for(int kc=0;kc<2;kc++){
    s8v bf[4];
    #pragma unroll
    for(int nt=0;nt<4;nt++)
      bf[nt] = *(const s8v*)(w2b + (nt*16+lr)*64 + kc*32 + lg*8);
    #pragma unroll
    for(int it=0;it<4;it++){
      int pix = w*64 + it*16 + lr;
      s8v a;
      #pragma unroll
      for(int j=0;j<8;j++) a[j] = (short)sG[(kc*32+lg*8+j)*268 + pix];
      #pragma unroll
      for(int nt=0;nt<4;nt++)
        o2[it][nt] = MFMA(a, bf[nt], o2[it][nt]);
    }
  }
  __syncthreads();  // sG reads done
  // write sO f32 [64oc][268]
  #pragma unroll
  for(int it=0;it<4;it++)
    #pragma unroll
    for(int nt=0;nt<4;nt++)
      *(f4*)&sO[(nt*16+lr)*268 + w*64 + it*16 + lg*4] = o2[it][nt];
  __syncthreads();
  // residual + coalesced store: 32 lanes cover 256 px of one oc-row
  {
    int oc = t>>5; int px = (t&31)*8;
    #pragma unroll
    for(int it=0;it<8;it++){
      int o = it*8 + oc;
      float4 ov0 = *(const float4*)&sO[o*268 + px];
      float4 ov1 = *(const float4*)&sO[o*268 + px + 4];
      const float* ub = u + ((size_t)(b*64+o))*NPIX + pix0 + px;
      float* ob = out + ((size_t)(b*64+o))*NPIX + pix0 + px;
      float4 uv0 = *(const float4*)(ub);
      float4 uv1 = *(const float4*)(ub + 4);
      float4 r0, r1;
      r0.x = ov0.x+uv0.x; r0.y = ov0.y+uv0.y; r0.z = ov0.z+uv0.z; r0.w = ov0.w+uv0.w;
      r1.x = ov1.x+uv1.x; r1.y = ov1.y+uv1.y; r1.z = ov1.z+uv1.z; r1.w = ov1.w+uv1.w;
      *(float4*)(ob)     = r0;
      *(float4*)(ob + 4) = r1;
    }
  }
}

// ---------------- host launch ----------------
extern "C" void kernel_launch(void* const* d_in, const int* in_sizes, int n_in,
                              void* d_out, int out_size, void* d_ws, size_t ws_size,
                              hipStream_t stream) {
  (void)in_sizes; (void)n_in; (void)out_size; (void)ws_size;
  const float* u        = (const float*)d_in[0];
  const float* gnw      = (const float*)d_in[1];
  const float* gnb      = (const float*)d_in[2];
  const float* w_in_proj= (const float*)d_in[3];
  const float* w_to_in  = (const float*)d_in[4];
  const float* px_win   = (const float*)d_in[5];
  const float* px_ln_g  = (const float*)d_in[6];
  const float* px_ln_b  = (const float*)d_in[7];
  const float* px_w1    = (const float*)d_in[8];
  const float* px_w2    = (const float*)d_in[9];
  const float* px_b2    = (const float*)d_in[10];
  const float* py_win   = (const float*)d_in[11];
  const float* py_ln_g  = (const float*)d_in[12];
  const float* py_ln_b  = (const float*)d_in[13];
  const float* py_w1    = (const float*)d_in[14];
  const float* py_w2    = (const float*)d_in[15];
  const float* py_b2    = (const float*)d_in[16];
  const float* kx_wqk   = (const float*)d_in[17];
  const float* ky_wqk   = (const float*)d_in[18];
  const float* out_w1   = (const float*)d_in[19];
  const float* out_w2   = (const float*)d_in[20];
  float* out = (float*)d_out;

  float* fw = (float*)d_ws;
  float* part  = fw + 0;        // 2048
  float* gnmv  = fw + 2048;     // 8
  float* pc    = fw + 4096;     // 262144 (consumed by k3; overlaid by qxb/kxTb at k4)
  float* poolx = fw + 266240;   // 65536
  float* ux    = fw + 397312;   // 131072
  float* uy    = fw + 528384;   // 131072
  float* istat = fw + 659456;   // 1024
  float* c0g   = fw + 660480;   // 512
  float* bias1 = fw + 660992;   // 256
  ushort_t* wpb = (ushort_t*)(fw + 661504);  // 32768 bf16
  ushort_t* W1b = (ushort_t*)(fw + 677888);  // 32768 bf16
  ushort_t* w2b = (ushort_t*)(fw + 694272);  // 4096 bf16
  float* ksum   = fw + 696320;  // 2048
  ushort_t* qxb  = (ushort_t*)(fw + 4096);
  ushort_t* kxTb = (ushort_t*)(fw + 135168);
  ushort_t* qyb  = (ushort_t*)(fw + 698368);
  ushort_t* kyTb = (ushort_t*)(fw + 829440);
  ushort_t* up2  = (ushort_t*)(fw + 960512);
  ushort_t* Cb = (ushort_t*)d_out;             // 8 MB: per-channel cores
  ushort_t* cT = (ushort_t*)d_out + 4194304;   // 4 MB: mixed cores (consumed before kf writes)

  k1_stats<<<dim3(1024), dim3(256), 0, stream>>>(u, part, pc, poolx);
  k8a_fold<<<dim3(4), dim3(256), 0, stream>>>(part, gnw, gnb, w_in_proj, out_w2, gnmv, wpb, c0g, w2b);
  k3_mfma<<<dim3(16), dim3(256), 0, stream>>>(poolx, pc, gnmv, gnw, gnb, w_to_in,
      px_win, px_ln_g, px_ln_b, px_w1, px_w2, px_b2,
      py_win, py_ln_g, py_ln_b, py_w1, py_w2, py_b2, ux, uy);
  k4_gemm<<<dim3(64), dim3(256), 0, stream>>>(ux, uy, kx_wqk, ky_wqk, qxb, kxTb, qyb, kyTb);
  k5s_sums<<<dim3(16), dim3(256), 0, stream>>>(kxTb, kyTb, ksum);
  k7a_core<<<dim3(256), dim3(512), 0, stream>>>(u, kxTb, kyTb, Cb);
  k7m_mix<<<dim3(256), dim3(256), 0, stream>>>(Cb, wpb, c0g, ksum, cT);
  k7b_heavy<<<dim3(512), dim3(256), 0, stream>>>(cT, qxb, qyb, up2, istat);
  k8b_fold<<<dim3(4), dim3(64), 0, stream>>>(istat, out_w1, W1b, bias1);
  kf_out<<<dim3(1024), dim3(256), 0, stream>>>(up2, W1b, bias1, w2b, u, out);
}

// Round 15
// 196.284 us; speedup vs baseline: 1.0783x; 1.0783x over previous
//
#include <hip/hip_runtime.h>
#include <math.h>

typedef unsigned short ushort_t;
typedef unsigned int uint_t;
typedef __attribute__((ext_vector_type(8))) short s8v;
typedef __attribute__((ext_vector_type(4))) float f4;

#define NPIX 65536
#define EPS_ 1e-5f

__device__ __forceinline__ float bf2f(ushort_t u){ return __uint_as_float(((uint_t)u)<<16); }
__device__ __forceinline__ ushort_t f2bf(float f){
  uint_t u = __float_as_uint(f);
  uint_t r = (u + 0x7fffu + ((u>>16)&1u)) >> 16;
  return (ushort_t)r;
}
__device__ __forceinline__ float bflo(uint_t p){ return __uint_as_float(p<<16); }
__device__ __forceinline__ float bfhi(uint_t p){ return __uint_as_float(p & 0xffff0000u); }
__device__ __forceinline__ uint_t packbf(float a, float b){ return (uint_t)f2bf(a) | ((uint_t)f2bf(b)<<16); }

__device__ __forceinline__ f4 MFMA(s8v a, s8v b, f4 c){
  return __builtin_amdgcn_mfma_f32_16x16x32_bf16(a, b, c, 0, 0, 0);
}

__device__ __forceinline__ float wave_sum(float v){
  #pragma unroll
  for(int m=32;m>=1;m>>=1) v += __shfl_xor(v, m, 64);
  return v;
}

// ---------------- K1: single-pass GN sums + col partials + row pools ----------------
__global__ __launch_bounds__(256) void k1_stats(const float* __restrict__ u,
    float* __restrict__ part, float* __restrict__ pc, float* __restrict__ poolx){
  int blk = blockIdx.x; int b = blk>>8; int c = (blk>>2)&63; int iq = blk&3;
  int t = threadIdx.x; int lane = t&63; int w = t>>6;
  const float* up = u + ((size_t)(b*64+c))*NPIX + iq*64*256;
  __shared__ float sCol[4][256];
  __shared__ float red[8];
  float4 cs4 = {0.f,0.f,0.f,0.f};
  float ss = 0.f;
  #pragma unroll 4
  for(int r16=0;r16<16;r16++){
    int r = w*16 + r16;
    float4 v = *(const float4*)(up + r*256 + lane*4);
    cs4.x+=v.x; cs4.y+=v.y; cs4.z+=v.z; cs4.w+=v.w;
    ss += v.x*v.x+v.y*v.y+v.z*v.z+v.w*v.w;
    float rs = wave_sum(v.x+v.y+v.z+v.w);
    if(lane==0) poolx[(b*256 + iq*64 + r)*64 + c] = rs*(1.f/256.f);
  }
  *(float4*)&sCol[w][lane*4] = cs4;
  float ssw = wave_sum(ss);
  if(lane==0) red[w] = ssw;
  __syncthreads();
  float colsum = sCol[0][t]+sCol[1][t]+sCol[2][t]+sCol[3][t];
  pc[((b*64+c)*4+iq)*256 + t] = colsum;
  float s1 = wave_sum(colsum);
  if(lane==0) red[4+w] = s1;
  __syncthreads();
  if(t==0){
    part[((b*64+c)*4+iq)*2]   = red[4]+red[5]+red[6]+red[7];
    part[((b*64+c)*4+iq)*2+1] = red[0]+red[1]+red[2]+red[3];
  }
}

// ---------------- K8a: GN finalize (inlined k2) + fold GN into w_in_proj + w2 bf16 ----------------
__global__ __launch_bounds__(256) void k8a_fold(const float* __restrict__ part,
    const float* __restrict__ gnw, const float* __restrict__ gnb,
    const float* __restrict__ w_in_proj, const float* __restrict__ out_w2,
    float* __restrict__ gnmv, ushort_t* __restrict__ wpb,
    float* __restrict__ c0g, ushort_t* __restrict__ w2b){
  int b = blockIdx.x; int t = threadIdx.x;
  __shared__ float scs[64], shs[64], sMV[2];
  if(t<64){
    float S1=0.f, S2=0.f;
    #pragma unroll
    for(int q=0;q<4;q++){
      S1 += part[((b*64+t)*4+q)*2];
      S2 += part[((b*64+t)*4+q)*2+1];
    }
    S1 = wave_sum(S1); S2 = wave_sum(S2);
    if(t==0){
      const float inv = 1.f/4194304.f;
      float m = S1*inv; float v = S2*inv - m*m;
      float rs = rsqrtf(v + EPS_);
      gnmv[b*2] = m; gnmv[b*2+1] = rs;
      sMV[0] = m; sMV[1] = rs;
    }
  }
  __syncthreads();
  if(t<64){
    float sc = sMV[1]*gnw[t];
    scs[t] = sc; shs[t] = gnb[t] - sMV[0]*sc;
  }
  __syncthreads();
  int oc = t>>1, h = t&1;
  float c0 = 0.f;
  for(int k=0;k<32;k++){
    int ch = h*32 + k;
    float wv = w_in_proj[oc*64 + ch];
    wpb[((size_t)b*128 + oc)*64 + ch] = f2bf(wv*scs[ch]);
    c0 += wv*shs[ch];
  }
  c0 += __shfl_xor(c0, 1, 64);
  if(h==0) c0g[b*128 + oc] = c0;
  if(b==0){
    for(int e=t;e<4096;e+=256) w2b[e] = f2bf(out_w2[e]);
  }
}

// ---------------- K8b: fold InstanceNorm into out_w1 ----------------
__global__ void k8b_fold(const float* __restrict__ istat,
    const float* __restrict__ out_w1, ushort_t* __restrict__ W1b,
    float* __restrict__ bias1){
  int b = blockIdx.x; int t = threadIdx.x;
  __shared__ float ms[128], rss[128];
  ms[t] = istat[(b*128+t)*2];       rss[t] = istat[(b*128+t)*2+1];
  ms[64+t] = istat[(b*128+64+t)*2]; rss[64+t] = istat[(b*128+64+t)*2+1];
  __syncthreads();
  float bias = 0.f;
  for(int ch=0;ch<128;ch++){
    float wv = out_w1[t*128 + ch];
    float wr = wv*rss[ch];
    W1b[((size_t)b*64 + t)*128 + ch] = f2bf(wr);
    bias += wr*ms[ch];
  }
  bias1[b*64 + t] = bias;
}

// ---------------- K3: MFMA pooled-path MLP chain ----------------
// grid 16 = side(1b)|b(2b)|mt(1b); M=128 tokens per block; full chain:
// pn -> t1 = pn@w_to_in^T -> hh = t1@win^T -> LN -> f1 = gelu(hh@w1^T) -> out = f1@w2^T + b2
__global__ __launch_bounds__(256) void k3_mfma(
    const float* __restrict__ poolx, const float* __restrict__ pc,
    const float* __restrict__ gnmv,
    const float* __restrict__ gnw, const float* __restrict__ gnb,
    const float* __restrict__ w_to_in,
    const float* __restrict__ xwin, const float* __restrict__ xlg, const float* __restrict__ xlb,
    const float* __restrict__ xw1, const float* __restrict__ xw2, const float* __restrict__ xb2,
    const float* __restrict__ ywin, const float* __restrict__ ylg, const float* __restrict__ ylb,
    const float* __restrict__ yw1, const float* __restrict__ yw2, const float* __restrict__ yb2,
    float* __restrict__ ux, float* __restrict__ uy){
  int blk = blockIdx.x;
  int side = blk>>3; int b = (blk>>1)&3; int mt = blk&1;
  int i0 = mt*128;
  const float* win = side ? ywin : xwin;
  const float* lnw = side ? ylg  : xlg;
  const float* lnb = side ? ylb  : xlb;
  const float* w1  = side ? yw1  : xw1;
  const float* w2  = side ? yw2  : xw2;
  const float* b2  = side ? yb2  : xb2;
  float* outp = side ? uy : ux;

  __shared__ __align__(16) ushort_t sA[128*136];
  __shared__ __align__(16) ushort_t sB[128*136];
  __shared__ __align__(16) ushort_t sW[128*136];
  __shared__ float sGw[64], sGb[64], sLg[64], sLb[64];
  float* sF = (float*)sA;

  int t = threadIdx.x; int lane = t&63; int w = t>>6; int lr = lane&15; int lgq = lane>>4;
  const f4 fz = {0.f,0.f,0.f,0.f};

  if(t<64){ sGw[t]=gnw[t]; sGb[t]=gnb[t]; sLg[t]=lnw[t]; sLb[t]=lnb[t]; }
  for(int e=t;e<2048;e+=256){
    int r = e>>5, c2 = e&31;
    *(uint_t*)&sW[r*136 + c2*2] = packbf(w_to_in[r*64 + c2*2], w_to_in[r*64 + c2*2 + 1]);
  }
  __syncthreads();
  {
    float mean = gnmv[b*2], rstd = gnmv[b*2+1];
    int chalf = t>>7, tok = t&127;
    if(side==0){
      const float* pb = poolx + ((size_t)(b*256 + i0 + tok))*64 + chalf*32;
      #pragma unroll 8
      for(int cc=0;cc<32;cc++){
        int c = chalf*32+cc;
        float pn = (pb[cc]-mean)*rstd*sGw[c] + sGb[c];
        sA[c*136 + tok] = f2bf(pn);
      }
    } else {
      #pragma unroll 4
      for(int cc=0;cc<32;cc++){
        int c = chalf*32+cc;
        const float* p = pc + ((size_t)(b*64+c)*4)*256 + (i0+tok);
        float pv = (p[0]+p[256]+p[512]+p[768])*(1.f/256.f);
        float pn = (pv-mean)*rstd*sGw[c] + sGb[c];
        sA[c*136 + tok] = f2bf(pn);
      }
    }
  }
  __syncthreads();
  {
    f4 acc[2][4];
    #pragma unroll
    for(int it=0;it<2;it++)
      #pragma unroll
      for(int nt=0;nt<4;nt++) acc[it][nt]=fz;
    #pragma unroll
    for(int kc=0;kc<2;kc++){
      s8v bf[4];
      #pragma unroll
      for(int nt=0;nt<4;nt++)
        bf[nt] = *(const s8v*)&sW[(nt*16+lr)*136 + kc*32 + lgq*8];
      #pragma unroll
      for(int it=0;it<2;it++){
        int tok = w*32 + it*16 + lr;
        s8v a;
        #pragma unroll
        for(int j=0;j<8;j++) a[j] = (short)sA[(kc*32+lgq*8+j)*136 + tok];
        #pragma unroll
        for(int nt=0;nt<4;nt++)
          acc[it][nt] = MFMA(a, bf[nt], acc[it][nt]);
      }
    }
    __syncthreads();
    #pragma unroll
    for(int it=0;it<2;it++)
      #pragma unroll
      for(int nt=0;nt<4;nt++){
        f4 v = acc[it][nt];
        uint2 pk; pk.x = packbf(v.x,v.y); pk.y = packbf(v.z,v.w);
        *(uint2*)&sB[(nt*16+lr)*136 + w*32 + it*16 + lgq*4] = pk;
      }
  }
  for(int e=t;e<2048;e+=256){
    int r = e>>5, c2 = e&31;
    *(uint_t*)&sW[r*136 + c2*2] = packbf(win[r*64 + c2*2], win[r*64 + c2*2 + 1]);
  }
  __syncthreads();
  {
    f4 acc[2][4];
    #pragma unroll
    for(int it=0;it<2;it++)
      #pragma unroll
      for(int nt=0;nt<4;nt++) acc[it][nt]=fz;
    #pragma unroll
    for(int kc=0;kc<2;kc++){
      s8v bf[4];
      #pragma unroll
      for(int nt=0;nt<4;nt++)
        bf[nt] = *(const s8v*)&sW[(nt*16+lr)*136 + kc*32 + lgq*8];
      #pragma unroll
      for(int it=0;it<2;it++){
        int tok = w*32 + it*16 + lr;
        s8v a;
        #pragma unroll
        for(int j=0;j<8;j++) a[j] = (short)sB[(kc*32+lgq*8+j)*136 + tok];
        #pragma unroll
        for(int nt=0;nt<4;nt++)
          acc[it][nt] = MFMA(bf[nt], a, acc[it][nt]);
      }
    }
    __syncthreads();
    #pragma unroll
    for(int it=0;it<2;it++)
      #pragma unroll
      for(int nt=0;nt<4;nt++)
        *(f4*)&sF[(size_t)(w*32+it*16+lr)*68 + nt*16 + lgq*4] = acc[it][nt];
  }
  __syncthreads();
  for(int e=t;e<4096;e+=256){
    int r = e>>5, c2 = e&31;
    *(uint_t*)&sW[r*136 + c2*2] = packbf(w1[r*64 + c2*2], w1[r*64 + c2*2 + 1]);
  }
  if(t<128){
    float s=0.f, ss=0.f;
    #pragma unroll 8
    for(int o=0;o<64;o++){ float v = sF[(size_t)t*68 + o]; s+=v; ss+=v*v; }
    float m2 = s*(1.f/64.f);
    float var = ss*(1.f/64.f) - m2*m2;
    float rs2 = rsqrtf(var + EPS_);
    #pragma unroll 8
    for(int o=0;o<64;o++){
      float lnv = (sF[(size_t)t*68 + o]-m2)*rs2*sLg[o] + sLb[o];
      sB[o*136 + t] = f2bf(lnv);
    }
  }
  __syncthreads();
  {
    f4 acc[2][8];
    #pragma unroll
    for(int it=0;it<2;it++)
      #pragma unroll
      for(int nt=0;nt<8;nt++) acc[it][nt]=fz;
    #pragma unroll
    for(int kc=0;kc<2;kc++){
      s8v bf[8];
      #pragma unroll
      for(int nt=0;nt<8;nt++)
        bf[nt] = *(const s8v*)&sW[(nt*16+lr)*136 + kc*32 + lgq*8];
      #pragma unroll
      for(int it=0;it<2;it++){
        int tok = w*32 + it*16 + lr;
        s8v a;
        #pragma unroll
        for(int j=0;j<8;j++) a[j] = (short)sB[(kc*32+lgq*8+j)*136 + tok];
        #pragma unroll
        for(int nt=0;nt<8;nt++)
          acc[it][nt] = MFMA(a, bf[nt], acc[it][nt]);
      }
    }
    __syncthreads();
    #pragma unroll
    for(int it=0;it<2;it++)
      #pragma unroll
      for(int nt=0;nt<8;nt++){
        f4 v = acc[it][nt];
        #pragma unroll
        for(int r=0;r<4;r++){
          float x = v[r];
          v[r] = 0.5f*x*(1.f + erff(x*0.70710678118654752f));
        }
        uint2 pk; pk.x = packbf(v[0],v[1]); pk.y = packbf(v[2],v[3]);
        *(uint2*)&sA[(nt*16+lr)*136 + w*32 + it*16 + lgq*4] = pk;
      }
  }
  __syncthreads();
  for(int e=t;e<8192;e+=256){
    int r = e>>6, c2 = e&63;
    *(uint_t*)&sW[r*136 + c2*2] = packbf(w2[r*128 + c2*2], w2[r*128 + c2*2 + 1]);
  }
  __syncthreads();
  {
    f4 acc[2][8];
    #pragma unroll
    for(int nt=0;nt<8;nt++){
      f4 bb = *(const f4*)&b2[nt*16 + lgq*4];
      acc[0][nt] = bb; acc[1][nt] = bb;
    }
    #pragma unroll
    for(int kc=0;kc<4;kc++){
      s8v bf[8];
      #pragma unroll
      for(int nt=0;nt<8;nt++)
        bf[nt] = *(const s8v*)&sW[(nt*16+lr)*136 + kc*32 + lgq*8];
      #pragma unroll
      for(int it=0;it<2;it++){
        int tok = w*32 + it*16 + lr;
        s8v a;
        #pragma unroll
        for(int j=0;j<8;j++) a[j] = (short)sA[(kc*32+lgq*8+j)*136 + tok];
        #pragma unroll
        for(int nt=0;nt<8;nt++)
          acc[it][nt] = MFMA(bf[nt], a, acc[it][nt]);
      }
    }
    #pragma unroll
    for(int it=0;it<2;it++){
      int tok = w*32 + it*16 + lr;
      #pragma unroll
      for(int nt=0;nt<8;nt++)
        *(f4*)&outp[((size_t)(b*256 + i0 + tok))*128 + nt*16 + lgq*4] = acc[it][nt];
    }
  }
}

// ---------------- K4: MFMA qk GEMM + fused RoPE ----------------
__global__ __launch_bounds__(256) void k4_gemm(
    const float* __restrict__ ux, const float* __restrict__ uy,
    const float* __restrict__ wqkx, const float* __restrict__ wqky,
    ushort_t* __restrict__ qxb, ushort_t* __restrict__ kxTb,
    ushort_t* __restrict__ qyb, ushort_t* __restrict__ kyTb){
  int blk = blockIdx.x;
  int nt = blk&3; int mt = (blk>>2)&1; int b = (blk>>3)&3; int side = blk>>5;
  const float* x  = (side? uy:ux) + (size_t)(b*256 + mt*128)*128;
  const float* wq = (side? wqky:wqkx) + (size_t)nt*128*128;
  ushort_t* qb  = side? qyb : qxb;
  ushort_t* kTb = side? kyTb : kxTb;

  __shared__ __align__(16) ushort_t sA[128*136];
  __shared__ __align__(16) ushort_t sB[128*136];

  int t = threadIdx.x; int lane = t&63; int w = t>>6; int lr = lane&15; int lg = lane>>4;
  for(int e=t;e<4096;e+=256){
    int row = e>>5, c4 = (e&31)*4;
    float4 v = *(const float4*)(x + row*128 + c4);
    uint2 pk; pk.x = packbf(v.x,v.y); pk.y = packbf(v.z,v.w);
    *(uint2*)&sA[row*136 + c4] = pk;
    float4 wv = *(const float4*)(wq + row*128 + c4);
    uint2 wk; wk.x = packbf(wv.x,wv.y); wk.y = packbf(wv.z,wv.w);
    *(uint2*)&sB[row*136 + c4] = wk;
  }
  __syncthreads();
  const f4 fz = {0.f,0.f,0.f,0.f};
  f4 acc[2][8];
  #pragma unroll
  for(int it=0;it<2;it++)
    #pragma unroll
    for(int n2=0;n2<8;n2++) acc[it][n2]=fz;
  #pragma unroll
  for(int kc=0;kc<4;kc++){
    s8v bf[8];
    #pragma unroll
    for(int n2=0;n2<8;n2++)
      bf[n2] = *(const s8v*)&sB[(n2*16+lr)*136 + kc*32 + lg*8];
    #pragma unroll
    for(int it=0;it<2;it++){
      s8v a = *(const s8v*)&sA[(w*32+it*16+lr)*136 + kc*32 + lg*8];
      #pragma unroll
      for(int n2=0;n2<8;n2++)
        acc[it][n2] = MFMA(a, bf[n2], acc[it][n2]);
    }
  }
  if(nt < 2){
    #pragma unroll
    for(int it=0;it<2;it++){
      #pragma unroll
      for(int n2=0;n2<8;n2++){
        int o = nt*128 + n2*16 + lr;
        int h = o>>6, dd = o&63, t32 = dd&31;
        float invf = expf(-(float)t32*(9.210340371976184f/32.f));
        size_t base = (size_t)(b*4+h)*16384;
        #pragma unroll
        for(int r=0;r<4;r++){
          int i = mt*128 + w*32 + it*16 + lg*4 + r;
          float f = (64.f/255.f)*(float)i*invf;
          float sn, cs; __sincosf(f, &sn, &cs);
          float pair = acc[it][n2^2][r];
          float rot = ((n2&2)==0)? -pair : pair;
          float v = acc[it][n2][r]*cs + rot*sn;
          qb[base + (size_t)i*64 + dd] = f2bf(v);
        }
      }
    }
  } else {
    __syncthreads();
    #pragma unroll
    for(int it=0;it<2;it++){
      #pragma unroll
      for(int n2=0;n2<8;n2++){
        int ol = n2*16 + lr;
        int o = nt*128 + ol;
        int t32 = o&31;
        float invf = expf(-(float)t32*(9.210340371976184f/32.f));
        #pragma unroll
        for(int r=0;r<4;r++){
          int il = w*32 + it*16 + lg*4 + r;
          int i = mt*128 + il;
          float f = (64.f/255.f)*(float)i*invf;
          float sn, cs; __sincosf(f, &sn, &cs);
          float pair = acc[it][n2^2][r];
          float rot = ((n2&2)==0)? -pair : pair;
          float v = acc[it][n2][r]*cs + rot*sn;
          sA[ol*136 + il] = f2bf(v);
        }
      }
    }
    __syncthreads();
    {
      int row = t>>1, half = t&1;
      int h = (nt-2)*2 + (row>>6), dd = row&63;
      ushort_t* dst = kTb + (size_t)(b*4+h)*16384 + (size_t)dd*256 + mt*128 + half*64;
      const ushort_t* src = &sA[row*136 + half*64];
      #pragma unroll
      for(int j=0;j<8;j++)
        *(uint4*)(dst + j*8) = *(const uint4*)(src + j*8);
    }
  }
}

// ---------------- K5s: row sums of KxT/KyT (rank-1 c0 term) ----------------
__global__ __launch_bounds__(256) void k5s_sums(const ushort_t* __restrict__ kxTb,
    const ushort_t* __restrict__ kyTb, float* __restrict__ ksum){
  int bh = blockIdx.x; int t = threadIdx.x;
  int row = t>>2, g = t&3;
  const ushort_t* kx = kxTb + (size_t)bh*16384 + row*256 + g*64;
  float s = 0.f;
  #pragma unroll
  for(int j=0;j<8;j++){
    uint4 v = *(const uint4*)(kx + j*8);
    s += bflo(v.x)+bfhi(v.x)+bflo(v.y)+bfhi(v.y)+bflo(v.z)+bfhi(v.z)+bflo(v.w)+bfhi(v.w);
  }
  s += __shfl_xor(s,1,64); s += __shfl_xor(s,2,64);
  if(g==0) ksum[bh*128 + row] = s;
  const ushort_t* ky = kyTb + (size_t)bh*16384 + row*256 + g*64;
  float s2 = 0.f;
  #pragma unroll
  for(int j=0;j<8;j++){
    uint4 v = *(const uint4*)(ky + j*8);
    s2 += bflo(v.x)+bfhi(v.x)+bflo(v.y)+bfhi(v.y)+bflo(v.z)+bfhi(v.z)+bflo(v.w)+bfhi(v.w);
  }
  s2 += __shfl_xor(s2,1,64); s2 += __shfl_xor(s2,2,64);
  if(g==0) ksum[bh*128 + 64 + row] = s2;
}

// ---------------- K7a: per-input-channel cores Chat[b][ch][h] = KxT * u_ch * Ky ----------------
__global__ __launch_bounds__(512) void k7a_core(
    const float* __restrict__ u,
    const ushort_t* __restrict__ kxTb, const ushort_t* __restrict__ kyTb,
    ushort_t* __restrict__ Cb){
  int blk = blockIdx.x; int b = blk>>6;
  const float* up = u + (size_t)blk*NPIX;
  __shared__ __align__(16) ushort_t su[2][64*264];
  __shared__ __align__(16) ushort_t sT1[4][64*68];
  int t = threadIdx.x; int w = t>>6; int lane = t&63; int lr = lane&15; int lg = lane>>4;
  int h = w>>1, sub = w&1;
  const ushort_t* KyT = kyTb + (size_t)(b*4+h)*16384;
  const ushort_t* KxT = kxTb + (size_t)(b*4+h)*16384;
  const f4 fz = {0.f,0.f,0.f,0.f};
  f4 cacc[2][4];
  #pragma unroll
  for(int it=0;it<2;it++)
    #pragma unroll
    for(int et=0;et<4;et++) cacc[it][et]=fz;

  auto stageld = [&](int jc, int buf){
    #pragma unroll
    for(int k=0;k<8;k++){
      int flat = k*512 + t;
      int row = flat>>6, col4 = flat&63;
      float4 v = *(const float4*)(up + (size_t)(jc*64+row)*256 + col4*4);
      uint2 pk; pk.x = packbf(v.x,v.y); pk.y = packbf(v.z,v.w);
      *(uint2*)&su[buf][row*264 + col4*4] = pk;
    }
  };
  stageld(0, 0);
  __syncthreads();
  for(int jc=0;jc<4;jc++){
    int cur = jc&1;
    f4 acc[2][4];
    #pragma unroll
    for(int jt=0;jt<2;jt++)
      #pragma unroll
      for(int et=0;et<4;et++) acc[jt][et]=fz;
    #pragma unroll
    for(int km=0;km<8;km++){
      s8v a0 = *(const s8v*)&su[cur][(sub*32+lr)*264 + km*32 + lg*8];
      s8v a1 = *(const s8v*)&su[cur][(sub*32+16+lr)*264 + km*32 + lg*8];
      #pragma unroll
      for(int et=0;et<4;et++){
        s8v bv = *(const s8v*)(KyT + (et*16+lr)*256 + km*32 + lg*8);
        acc[0][et] = MFMA(a0,bv,acc[0][et]);
        acc[1][et] = MFMA(a1,bv,acc[1][et]);
      }
    }
    #pragma unroll
    for(int jt=0;jt<2;jt++)
      #pragma unroll
      for(int et=0;et<4;et++){
        f4 v = acc[jt][et];
        uint2 pk; pk.x=packbf(v.x,v.y); pk.y=packbf(v.z,v.w);
        *(uint2*)&sT1[h][(et*16+lr)*68 + sub*32 + jt*16 + lg*4] = pk;
      }
    __syncthreads();
    if(jc<3) stageld(jc+1, cur^1);
    #pragma unroll
    for(int kj=0;kj<2;kj++){
      s8v a0 = *(const s8v*)(KxT + (size_t)(sub*32+lr)*256 + jc*64 + kj*32 + lg*8);
      s8v a1 = *(const s8v*)(KxT + (size_t)(sub*32+16+lr)*256 + jc*64 + kj*32 + lg*8);
      #pragma unroll
      for(int et=0;et<4;et++){
        s8v bv = *(const s8v*)&sT1[h][(et*16+lr)*68 + kj*32 + lg*8];
        cacc[0][et] = MFMA(a0,bv,cacc[0][et]);
        cacc[1][et] = MFMA(a1,bv,cacc[1][et]);
      }
    }
    __syncthreads();
  }
  ushort_t* cbase = Cb + ((size_t)blk*4 + h)*4096;
  #pragma unroll
  for(int it=0;it<2;it++)
    #pragma unroll
    for(int et=0;et<4;et++){
      f4 v = cacc[it][et];
      uint2 pk; pk.x=packbf(v.x,v.y); pk.y=packbf(v.z,v.w);
      *(uint2*)&cbase[(et*16+lr)*64 + sub*32 + it*16 + lg*4] = pk;
    }
}

// ---------------- K7m: mix cores across input channels (+rank-1 c0 term) ----------------
__global__ __launch_bounds__(256) void k7m_mix(
    const ushort_t* __restrict__ Cb, const ushort_t* __restrict__ wpb,
    const float* __restrict__ c0g, const float* __restrict__ ksum,
    ushort_t* __restrict__ cT){
  int blk = blockIdx.x; int bh = blk>>4; int et = blk&15;
  int b = bh>>2, h = bh&3;
  __shared__ __align__(16) ushort_t sC[64*264];
  __shared__ float sWf[32*64];
  __shared__ float sKx[64], sKy4[4];
  int t = threadIdx.x;
  #pragma unroll
  for(int k=0;k<8;k++){
    int flat = k*256 + t;
    int ic = flat>>5, q = flat&31;
    uint4 v = *(const uint4*)(Cb + ((size_t)(b*64+ic)*4 + h)*4096 + et*256 + q*8);
    *(uint4*)&sC[ic*264 + q*8] = v;
  }
  for(int e=t;e<2048;e+=256){
    int ch = e>>6, ic = e&63;
    sWf[e] = bf2f(wpb[((size_t)b*128 + h*32 + ch)*64 + ic]);
  }
  if(t<64) sKx[t] = ksum[bh*128 + t];
  if(t<4)  sKy4[t] = ksum[bh*128 + 64 + et*4 + t];
  __syncthreads();
  int chg = t>>5, edq = t&31, ed0 = edq*8;
  float c0v[4];
  #pragma unroll
  for(int cc=0;cc<4;cc++) c0v[cc] = c0g[b*128 + h*32 + chg*4 + cc];
  float acc[4][8];
  #pragma unroll
  for(int j=0;j<8;j++){
    int ed = ed0 + j;
    float r1 = sKy4[ed>>6]*sKx[ed&63];
    #pragma unroll
    for(int cc=0;cc<4;cc++) acc[cc][j] = c0v[cc]*r1;
  }
  for(int ic=0;ic<64;ic++){
    uint4 cv = *(const uint4*)&sC[ic*264 + ed0];
    float x[8];
    x[0]=bflo(cv.x); x[1]=bfhi(cv.x); x[2]=bflo(cv.y); x[3]=bfhi(cv.y);
    x[4]=bflo(cv.z); x[5]=bfhi(cv.z); x[6]=bflo(cv.w); x[7]=bfhi(cv.w);
    #pragma unroll
    for(int cc=0;cc<4;cc++){
      float wv = sWf[(chg*4+cc)*64 + ic];
      #pragma unroll
      for(int j=0;j<8;j++) acc[cc][j] += wv*x[j];
    }
  }
  #pragma unroll
  for(int cc=0;cc<4;cc++){
    uint2 p0, p1;
    p0.x = packbf(acc[cc][0],acc[cc][1]); p0.y = packbf(acc[cc][2],acc[cc][3]);
    p1.x = packbf(acc[cc][4],acc[cc][5]); p1.y = packbf(acc[cc][6],acc[cc][7]);
    ushort_t* dst = cT + ((size_t)bh*32 + chg*4+cc)*4096 + et*256 + ed0;
    *(uint2*)(dst) = p0;
    *(uint2*)(dst+4) = p1;
  }
}

// ---------------- K7b: expand out_c = Qx core_c Qy^T + stats ----------------
__global__ __launch_bounds__(256) void k7b_heavy(
    const ushort_t* __restrict__ cT,
    const ushort_t* __restrict__ qxb, const ushort_t* __restrict__ qyb,
    ushort_t* __restrict__ up2, float* __restrict__ istat){
  int blk = blockIdx.x;
  int c = blk & 31; int h = (blk>>5)&3; int b = blk>>7;
  int bh = b*4 + h; int ch = h*32 + c;
  const ushort_t* Qx  = qxb + (size_t)bh*16384;
  const ushort_t* Qy  = qyb + (size_t)bh*16384;
  const ushort_t* cTc = cT + (size_t)(bh*32 + c)*4096;
  ushort_t* out_c = up2 + (size_t)(b*128 + ch)*NPIX;

  __shared__ __align__(16) ushort_t sP[256*72];
  __shared__ float sRed[8];

  int t = threadIdx.x; int w = t>>6; int lane = t&63; int lr = lane&15; int lg = lane>>4;
  const f4 fz = {0.f,0.f,0.f,0.f};
  {
    s8v aF[4][2];
    #pragma unroll
    for(int me=0;me<4;me++)
      #pragma unroll
      for(int kd=0;kd<2;kd++)
        aF[me][kd] = *(const s8v*)(cTc + (me*16+lr)*64 + kd*32 + lg*8);
    #pragma unroll
    for(int it=0;it<4;it++){
      s8v b0 = *(const s8v*)(Qx + (w*64+it*16+lr)*64 + lg*8);
      s8v b1 = *(const s8v*)(Qx + (w*64+it*16+lr)*64 + 32 + lg*8);
      #pragma unroll
      for(int me=0;me<4;me++){
        f4 pv = MFMA(aF[me][0], b0, fz);
        pv = MFMA(aF[me][1], b1, pv);
        uint2 pk; pk.x=packbf(pv.x,pv.y); pk.y=packbf(pv.z,pv.w);
        *(uint2*)&sP[(w*64+it*16+lr)*72 + me*16 + lg*4] = pk;
      }
    }
  }
  __syncthreads();
  float lsum=0.f, lssq=0.f;
  {
    s8v aP[4][2];
    #pragma unroll
    for(int it=0;it<4;it++)
      #pragma unroll
      for(int ke=0;ke<2;ke++)
        aP[it][ke] = *(const s8v*)&sP[(w*64+it*16+lr)*72 + ke*32 + lg*8];
    for(int lt=0;lt<4;lt++){
      s8v bq[4][2];
      #pragma unroll
      for(int nt=0;nt<4;nt++)
        #pragma unroll
        for(int ke=0;ke<2;ke++)
          bq[nt][ke] = *(const s8v*)(Qy + (lt*64+nt*16+lr)*64 + ke*32 + lg*8);
      #pragma unroll
      for(int it=0;it<4;it++){
        #pragma unroll
        for(int nt=0;nt<4;nt++){
          f4 o = MFMA(bq[nt][0], aP[it][0], fz);
          o = MFMA(bq[nt][1], aP[it][1], o);
          lsum += o[0]+o[1]+o[2]+o[3];
          lssq += o[0]*o[0]+o[1]*o[1]+o[2]*o[2]+o[3]*o[3];
          uint2 pk; pk.x = packbf(o[0],o[1]); pk.y = packbf(o[2],o[3]);
          *(uint2*)(out_c + (size_t)(w*64 + it*16 + lr)*256 + lt*64 + nt*16 + lg*4) = pk;
        }
      }
    }
  }
  float a1 = wave_sum(lsum), a2 = wave_sum(lssq);
  if(lane==0){ sRed[w]=a1; sRed[4+w]=a2; }
  __syncthreads();
  if(t==0){
    float S = sRed[0]+sRed[1]+sRed[2]+sRed[3];
    float SS = sRed[4]+sRed[5]+sRed[6]+sRed[7];
    float m = S*(1.f/65536.f);
    float var = SS*(1.f/65536.f) - m*m;
    istat[(b*128+ch)*2] = m;
    istat[(b*128+ch)*2+1] = rsqrtf(var + EPS_);
  }
}

// ---------------- KF: MFMA InstanceNorm(folded)+conv1-GELU-conv2+residual ----------------
__global__ __launch_bounds__(256) void kf_out(
    const ushort_t* __restrict__ up2, const ushort_t* __restrict__ W1b,
    const float* __restrict__ bias1, const ushort_t* __restrict__ w2b,
    const float* __restrict__ u, float* __restrict__ out){
  int blk = blockIdx.x;
  int b = blk>>9; int pix0 = (blk&511)<<7;
  __shared__ __align__(16) unsigned char smraw[128*132*2];
  ushort_t* sX = (ushort_t*)smraw;
  ushort_t* sG = (ushort_t*)smraw;
  float* sO = (float*)smraw;
  int t = threadIdx.x; int lane = t&63; int w = t>>6; int lr = lane&15; int lg = lane>>4;
  {
    int ch = t>>4; int px = (t&15)*8;
    #pragma unroll
    for(int it=0; it<8; it++){
      int c = it*16 + ch;
      uint4 v = *(const uint4*)(up2 + ((size_t)(b*128+c))*NPIX + pix0 + px);
      uint2 lo; lo.x = v.x; lo.y = v.y;
      uint2 hi; hi.x = v.z; hi.y = v.w;
      *(uint2*)&sX[c*132 + px] = lo;
      *(uint2*)&sX[c*132 + px + 4] = hi;
    }
  }
  __syncthreads();
  const ushort_t* w1p = W1b + (size_t)b*64*128;
  f4 g[2][4];
  #pragma unroll
  for(int it=0;it<2;it++)
    #pragma unroll
    for(int nt=0;nt<4;nt++){
      float bv = -bias1[b*64 + nt*16 + lr];
      f4 ci = {bv,bv,bv,bv};
      g[it][nt] = ci;
    }
  #pragma unroll
  for(int kc=0;kc<4;kc++){
    s8v bf[4];
    #pragma unroll
    for(int nt=0;nt<4;nt++)
      bf[nt] = *(const s8v*)(w1p + (nt*16+lr)*128 + kc*32 + lg*8);
    #pragma unroll
    for(int it=0;it<2;it++){
      int pix = w*32 + it*16 + lr;
      s8v a;
      #pragma unroll
      for(int j=0;j<8;j++) a[j] = (short)sX[(kc*32+lg*8+j)*132 + pix];
      #pragma unroll
      for(int nt=0;nt<4;nt++)
        g[it][nt] = MFMA(a, bf[nt], g[it][nt]);
    }
  }
  #pragma unroll
  for(int it=0;it<2;it++)
    #pragma unroll
    for(int nt=0;nt<4;nt++){
      f4 v = g[it][nt];
      #pragma unroll
      for(int r=0;r<4;r++){
        float x = v[r];
        v[r] = 0.5f*x*(1.f + erff(x*0.70710678118654752f));
      }
      g[it][nt] = v;
    }
  __syncthreads();
  #pragma unroll
  for(int it=0;it<2;it++)
    #pragma unroll
    for(int nt=0;nt<4;nt++){
      f4 v = g[it][nt];
      uint2 pk; pk.x = packbf(v.x,v.y); pk.y = packbf(v.z,v.w);
      *(uint2*)&sG[(nt*16+lr)*132 + w*32 + it*16 + lg*4] = pk;
    }
  __syncthreads();
  f4 o2[2][4];
  const f4 fz = {0.f,0.f,0.f,0.f};
  #pragma unroll
  for(int it=0;it<2;it++)
    #pragma unroll
    for(int nt=0;nt<4;nt++) o2[it][nt]=fz;
  #pragma unroll
  for(int kc=0;kc<2;kc++){
    s8v bf[4];
    #pragma unroll
    for(int nt=0;nt<4;nt++)
      bf[nt] = *(const s8v*)(w2b + (nt*16+lr)*64 + kc*32 + lg*8);
    #pragma unroll
    for(int it=0;it<2;it++){
      int pix = w*32 + it*16 + lr;
      s8v a;
      #pragma unroll
      for(int j=0;j<8;j++) a[j] = (short)sG[(kc*32+lg*8+j)*132 + pix];
      #pragma unroll
      for(int nt=0;nt<4;nt++)
        o2[it][nt] = MFMA(a, bf[nt], o2[it][nt]);
    }
  }
  __syncthreads();
  #pragma unroll
  for(int it=0;it<2;it++)
    #pragma unroll
    for(int nt=0;nt<4;nt++)
      *(f4*)&sO[(nt*16+lr)*132 + w*32 + it*16 + lg*4] = o2[it][nt];
  __syncthreads();
  {
    int oc = t>>5; int px = (t&31)*4;
    #pragma unroll
    for(int it=0;it<8;it++){
      int o = it*8 + oc;
      float4 ov = *(const float4*)&sO[o*132 + px];
      float4 uv = *(const float4*)(u + ((size_t)(b*64+o))*NPIX + pix0 + px);
      float4 rv;
      rv.x = ov.x+uv.x; rv.y = ov.y+uv.y; rv.z = ov.z+uv.z; rv.w = ov.w+uv.w;
      *(float4*)(out + ((size_t)(b*64+o))*NPIX + pix0 + px) = rv;
    }
  }
}

// ---------------- host launch ----------------
extern "C" void kernel_launch(void* const* d_in, const int* in_sizes, int n_in,
                              void* d_out, int out_size, void* d_ws, size_t ws_size,
                              hipStream_t stream) {
  (void)in_sizes; (void)n_in; (void)out_size; (void)ws_size;
  const float* u        = (const float*)d_in[0];
  const float* gnw      = (const float*)d_in[1];
  const float* gnb      = (const float*)d_in[2];
  const float* w_in_proj= (const float*)d_in[3];
  const float* w_to_in  = (const float*)d_in[4];
  const float* px_win   = (const float*)d_in[5];
  const float* px_ln_g  = (const float*)d_in[6];
  const float* px_ln_b  = (const float*)d_in[7];
  const float* px_w1    = (const float*)d_in[8];
  const float* px_w2    = (const float*)d_in[9];
  const float* px_b2    = (const float*)d_in[10];
  const float* py_win   = (const float*)d_in[11];
  const float* py_ln_g  = (const float*)d_in[12];
  const float* py_ln_b  = (const float*)d_in[13];
  const float* py_w1    = (const float*)d_in[14];
  const float* py_w2    = (const float*)d_in[15];
  const float* py_b2    = (const float*)d_in[16];
  const float* kx_wqk   = (const float*)d_in[17];
  const float* ky_wqk   = (const float*)d_in[18];
  const float* out_w1   = (const float*)d_in[19];
  const float* out_w2   = (const float*)d_in[20];
  float* out = (float*)d_out;

  float* fw = (float*)d_ws;
  float* part  = fw + 0;        // 2048
  float* gnmv  = fw + 2048;     // 8
  float* pc    = fw + 4096;     // 262144 (consumed by k3; overlaid by qxb/kxTb at k4)
  float* poolx = fw + 266240;   // 65536
  float* ux    = fw + 397312;   // 131072
  float* uy    = fw + 528384;   // 131072
  float* istat = fw + 659456;   // 1024
  float* c0g   = fw + 660480;   // 512
  float* bias1 = fw + 660992;   // 256
  ushort_t* wpb = (ushort_t*)(fw + 661504);  // 32768 bf16
  ushort_t* W1b = (ushort_t*)(fw + 677888);  // 32768 bf16
  ushort_t* w2b = (ushort_t*)(fw + 694272);  // 4096 bf16
  float* ksum   = fw + 696320;  // 2048
  ushort_t* qxb  = (ushort_t*)(fw + 4096);
  ushort_t* kxTb = (ushort_t*)(fw + 135168);
  ushort_t* qyb  = (ushort_t*)(fw + 698368);
  ushort_t* kyTb = (ushort_t*)(fw + 829440);
  ushort_t* up2  = (ushort_t*)(fw + 960512);
  ushort_t* Cb = (ushort_t*)d_out;             // 8 MB: per-channel cores
  ushort_t* cT = (ushort_t*)d_out + 4194304;   // 4 MB: mixed cores (consumed before kf writes)

  k1_stats<<<dim3(1024), dim3(256), 0, stream>>>(u, part, pc, poolx);
  k8a_fold<<<dim3(4), dim3(256), 0, stream>>>(part, gnw, gnb, w_in_proj, out_w2, gnmv, wpb, c0g, w2b);
  k3_mfma<<<dim3(16), dim3(256), 0, stream>>>(poolx, pc, gnmv, gnw, gnb, w_to_in,
      px_win, px_ln_g, px_ln_b, px_w1, px_w2, px_b2,
      py_win, py_ln_g, py_ln_b, py_w1, py_w2, py_b2, ux, uy);
  k4_gemm<<<dim3(64), dim3(256), 0, stream>>>(ux, uy, kx_wqk, ky_wqk, qxb, kxTb, qyb, kyTb);
  k5s_sums<<<dim3(16), dim3(256), 0, stream>>>(kxTb, kyTb, ksum);
  k7a_core<<<dim3(256), dim3(512), 0, stream>>>(u, kxTb, kyTb, Cb);
  k7m_mix<<<dim3(256), dim3(256), 0, stream>>>(Cb, wpb, c0g, ksum, cT);
  k7b_heavy<<<dim3(512), dim3(256), 0, stream>>>(cT, qxb, qyb, up2, istat);
  k8b_fold<<<dim3(4), dim3(64), 0, stream>>>(istat, out_w1, W1b, bias1);
  kf_out<<<dim3(2048), dim3(256), 0, stream>>>(up2, W1b, bias1, w2b, u, out);
}